// Round 2
// baseline (12859.323 us; speedup 1.0000x reference)
//
#include <hip/hip_runtime.h>

#define BB 64
#define SS 448
#define S1 449
#define DD 512
#define HH 8
#define LL 6
#define TT 3
#define FF 3072
#define NS 28672
#define N1 28736
#define N1P 28800
#define FBROWS 3712   // 29*128 max FFN chunk rows

typedef unsigned short u16;
typedef __attribute__((ext_vector_type(8))) short short8;
typedef __attribute__((ext_vector_type(4))) float floatx4;

#define AS1C(p) ((const __attribute__((address_space(1))) void*)(p))
#define AS3P(p) ((__attribute__((address_space(3))) void*)(p))

__device__ __forceinline__ float b2f(u16 u){
  union { float f; unsigned u; } x; x.u = ((unsigned)u) << 16; return x.f;
}
__device__ __forceinline__ u16 f2b(float f){
  union { float f; unsigned u; } x; x.f = f;
  unsigned r = x.u + 0x7FFFu + ((x.u >> 16) & 1u);
  return (u16)(r >> 16);
}
__device__ __forceinline__ float gelu_f(float v){ return 0.5f*v*(1.f+erff(v*0.70710678118654752440f)); }
__device__ __forceinline__ float sigm_f(float v){ return 1.f/(1.f+expf(-v)); }

// 256-thread (4-wave) block reduction of two values
__device__ __forceinline__ void reduce2(float& a, float& b, float* scr){
  #pragma unroll
  for (int off=1; off<64; off<<=1){ a += __shfl_xor(a, off); b += __shfl_xor(b, off); }
  const int w = threadIdx.x >> 6;
  __syncthreads();
  if ((threadIdx.x & 63) == 0){ scr[w] = a; scr[4+w] = b; }
  __syncthreads();
  a = scr[0]+scr[1]+scr[2]+scr[3];
  b = scr[4]+scr[5]+scr[6]+scr[7];
}

// ---------------- transpose + fp32->bf16 convert: dst[n][k] = src[k][n] ----------------
__global__ void transcvt(const float* __restrict__ src, u16* __restrict__ dst, int K, int N){
  __shared__ float t[32][33];
  const size_t bo = (size_t)blockIdx.z * K * N;
  src += bo; dst += bo;
  const int k0 = blockIdx.x*32, n0 = blockIdx.y*32;
  const int tx = threadIdx.x, ty = threadIdx.y;
  #pragma unroll
  for (int i=0;i<32;i+=8) t[ty+i][tx] = src[(size_t)(k0+ty+i)*N + n0+tx];
  __syncthreads();
  #pragma unroll
  for (int i=0;i<32;i+=8) dst[(size_t)(n0+ty+i)*K + k0+tx] = f2b(t[tx][ty+i]);
}

__global__ void cvt(const float* __restrict__ src, u16* __restrict__ dst, int n){
  int i = blockIdx.x*256 + threadIdx.x;
  if (i < n) dst[i] = f2b(src[i]);
}

// ---------------- bf16 MFMA GEMM: C[M,N] = act(A[M,K] @ Bt[N,K]^T + bias[N]) ----------------
// 128x128 tile, BK=32, 4 waves each 64x64 (4x4 of 16x16x32 MFMA). M%128==0, N%128==0, K%32==0.
template<int ACT, int HASMUL>
__launch_bounds__(256)
__global__ void gemm128(const u16* __restrict__ A, int lda,
                        const u16* __restrict__ Bt, int ldb,
                        const float* __restrict__ bias,
                        u16* __restrict__ Cp, int ldc,
                        const u16* __restrict__ mulp,
                        int K)
{
  __shared__ u16 Al[4096];
  __shared__ u16 Bl[4096];
  const int tid = threadIdx.x;
  const int lane = tid & 63;
  const int w = tid >> 6;
  const int wm = (w >> 1) * 64;
  const int wn = (w & 1) * 64;
  const size_t m0 = (size_t)blockIdx.x * 128;
  const size_t n0 = (size_t)blockIdx.y * 128;

  const int c1 = 256 + tid;
  const u16* a0 = A + (m0 + (tid>>2))*lda + (tid&3)*8;
  const u16* a1 = A + (m0 + (c1>>2))*lda + (c1&3)*8;
  const u16* b0 = Bt + (n0 + (tid>>2))*ldb + (tid&3)*8;
  const u16* b1 = Bt + (n0 + (c1>>2))*ldb + (c1&3)*8;

  const floatx4 fz = {0.f,0.f,0.f,0.f};
  floatx4 acc[4][4];
  #pragma unroll
  for (int i=0;i<4;i++)
    #pragma unroll
    for (int j=0;j<4;j++) acc[i][j] = fz;

  const int fr = lane & 15;
  const int fq = (lane >> 4) * 8;

  for (int k0 = 0; k0 < K; k0 += 32) {
    __syncthreads();
    __builtin_amdgcn_global_load_lds(AS1C(a0), AS3P(Al + w*512),        16, 0, 0);
    __builtin_amdgcn_global_load_lds(AS1C(a1), AS3P(Al + 2048 + w*512), 16, 0, 0);
    __builtin_amdgcn_global_load_lds(AS1C(b0), AS3P(Bl + w*512),        16, 0, 0);
    __builtin_amdgcn_global_load_lds(AS1C(b1), AS3P(Bl + 2048 + w*512), 16, 0, 0);
    a0 += 32; a1 += 32; b0 += 32; b1 += 32;
    __syncthreads();
    short8 af[4], bf[4];
    #pragma unroll
    for (int i=0;i<4;i++) af[i] = *(const short8*)(Al + (wm + i*16 + fr)*32 + fq);
    #pragma unroll
    for (int j=0;j<4;j++) bf[j] = *(const short8*)(Bl + (wn + j*16 + fr)*32 + fq);
    #pragma unroll
    for (int i=0;i<4;i++)
      #pragma unroll
      for (int j=0;j<4;j++)
        acc[i][j] = __builtin_amdgcn_mfma_f32_16x16x32_bf16(af[i], bf[j], acc[i][j], 0, 0, 0);
  }

  const int cr = (lane >> 4) * 4;
  const int cc = lane & 15;
  #pragma unroll
  for (int i=0;i<4;i++) {
    #pragma unroll
    for (int j=0;j<4;j++) {
      const size_t gc = n0 + wn + j*16 + cc;
      const float bv = bias[gc];
      #pragma unroll
      for (int r=0;r<4;r++) {
        const size_t gr = m0 + wm + i*16 + cr + r;
        float vv = acc[i][j][r] + bv;
        if (ACT==1) vv = gelu_f(vv);
        if (ACT==2) vv = sigm_f(vv);
        if (HASMUL) vv *= b2f(mulp[gr*ldc + gc]);
        Cp[gr*ldc + gc] = f2b(vv);
      }
    }
  }
}

// ---------------- flash attention (bf16 MFMA, fp32 softmax) ----------------
// grid = B*H*8 ; block 256 = 4 waves, each wave: 16 queries x full dk=64
__launch_bounds__(256)
__global__ void flash_attn(const u16* __restrict__ qg, const u16* __restrict__ kg,
                           const u16* __restrict__ vg, u16* __restrict__ ctx)
{
  const int bid = blockIdx.x;
  const int qt = bid & 7;
  const int h  = (bid >> 3) & 7;
  const int b  = bid >> 6;
  const int tid = threadIdx.x;
  const int lane = tid & 63;
  const int w = tid >> 6;

  __shared__ u16 Kl[32*64];
  __shared__ u16 Vt[64*72];    // stride 72 elements = 144 B (16B-aligned rows, 4-bank rotation)
  __shared__ u16 Pl[4][16*32];

  const int fr = lane & 15;
  const int fq = (lane >> 4) * 8;

  const int qrow = qt*64 + w*16;
  const size_t qoff = ((size_t)b*S1 + qrow + fr)*DD + h*64 + fq;
  const short8 qf0 = *(const short8*)(qg + qoff);
  const short8 qf1 = *(const short8*)(qg + qoff + 32);

  const floatx4 fz = {0.f,0.f,0.f,0.f};
  floatx4 oacc[4] = {fz, fz, fz, fz};
  float mm[4] = {-3e30f,-3e30f,-3e30f,-3e30f};
  float ll[4] = {0.f,0.f,0.f,0.f};

  const int key_t = tid >> 3;
  const int kch  = tid & 7;
  const u16* gk_base = kg + ((size_t)b*S1 + key_t)*DD + h*64 + kch*8;
  const u16* gv_base = vg + ((size_t)b*S1 + key_t)*DD + h*64 + kch*8;

  for (int k0 = 0; k0 < 480; k0 += 32) {
    __syncthreads();
    __builtin_amdgcn_global_load_lds(AS1C(gk_base + (size_t)k0*DD), AS3P(Kl + w*512), 16, 0, 0);
    {
      short8 tv = *(const short8*)(gv_base + (size_t)k0*DD);
      #pragma unroll
      for (int i=0;i<8;i++) Vt[(kch*8+i)*72 + key_t] = (u16)tv[i];
    }
    __syncthreads();

    floatx4 s0 = fz, s1 = fz;
    {
      short8 kb0  = *(const short8*)(Kl + (size_t)fr*64 + fq);
      short8 kb0h = *(const short8*)(Kl + (size_t)fr*64 + 32 + fq);
      s0 = __builtin_amdgcn_mfma_f32_16x16x32_bf16(qf0, kb0,  s0, 0,0,0);
      s0 = __builtin_amdgcn_mfma_f32_16x16x32_bf16(qf1, kb0h, s0, 0,0,0);
      short8 kb1  = *(const short8*)(Kl + (size_t)(16+fr)*64 + fq);
      short8 kb1h = *(const short8*)(Kl + (size_t)(16+fr)*64 + 32 + fq);
      s1 = __builtin_amdgcn_mfma_f32_16x16x32_bf16(qf0, kb1,  s1, 0,0,0);
      s1 = __builtin_amdgcn_mfma_f32_16x16x32_bf16(qf1, kb1h, s1, 0,0,0);
    }
    const bool msk0 = (k0 + fr) >= S1;
    const bool msk1 = (k0 + 16 + fr) >= S1;
    float p0[4], p1[4];
    #pragma unroll
    for (int r=0;r<4;r++) {
      p0[r] = msk0 ? -3e30f : s0[r]*0.125f;
      p1[r] = msk1 ? -3e30f : s1[r]*0.125f;
    }
    #pragma unroll
    for (int r=0;r<4;r++) {
      float t = fmaxf(p0[r], p1[r]);
      t = fmaxf(t, __shfl_xor(t,1)); t = fmaxf(t, __shfl_xor(t,2));
      t = fmaxf(t, __shfl_xor(t,4)); t = fmaxf(t, __shfl_xor(t,8));
      float mn = fmaxf(mm[r], t);
      float al = __expf(mm[r]-mn);
      mm[r] = mn;
      float e0 = msk0 ? 0.f : __expf(p0[r]-mn);
      float e1 = msk1 ? 0.f : __expf(p1[r]-mn);
      p0[r]=e0; p1[r]=e1;
      float rs = e0+e1;
      rs += __shfl_xor(rs,1); rs += __shfl_xor(rs,2);
      rs += __shfl_xor(rs,4); rs += __shfl_xor(rs,8);
      ll[r] = ll[r]*al + rs;
      oacc[0][r]*=al; oacc[1][r]*=al; oacc[2][r]*=al; oacc[3][r]*=al;
    }
    const int pr = (lane>>4)*4;
    #pragma unroll
    for (int r=0;r<4;r++) {
      Pl[w][(pr+r)*32 + fr]      = f2b(p0[r]);
      Pl[w][(pr+r)*32 + 16 + fr] = f2b(p1[r]);
    }
    short8 pf = *(const short8*)(&Pl[w][fr*32 + fq]);
    #pragma unroll
    for (int j=0;j<4;j++) {
      short8 vb = *(const short8*)(Vt + (size_t)(j*16+fr)*72 + fq);
      oacc[j] = __builtin_amdgcn_mfma_f32_16x16x32_bf16(pf, vb, oacc[j], 0,0,0);
    }
  }
  const int pr = (lane>>4)*4;
  #pragma unroll
  for (int r=0;r<4;r++) {
    const int qi = qrow + pr + r;
    if (qi < S1) {
      const size_t base = ((size_t)b*S1 + qi)*DD + h*64 + fr;
      const float inv = 1.f/ll[r];
      ctx[base]    = f2b(oacc[0][r]*inv);
      ctx[base+16] = f2b(oacc[1][r]*inv);
      ctx[base+32] = f2b(oacc[2][r]*inv);
      ctx[base+48] = f2b(oacc[3][r]*inv);
    }
  }
}

// ---------------- input stage: LN + pos + cls concat ----------------
__global__ void ln_pos_cls(const u16* __restrict__ t2, const float* __restrict__ lw,
                           const float* __restrict__ lb, const float* __restrict__ pos,
                           const float* __restrict__ cls, u16* __restrict__ h16)
{
  __shared__ float scr[8];
  const int row = blockIdx.x;
  const int b = row / S1, s = row % S1;
  const int tid = threadIdx.x;
  if (s == 0) {
    #pragma unroll
    for (int e=0;e<2;e++){ int d = tid + e*256; h16[(size_t)row*DD+d]=f2b(cls[d]); }
    return;
  }
  const u16* x = t2 + ((size_t)b*SS + (s-1))*DD;
  float v0 = b2f(x[tid]), v1 = b2f(x[tid+256]);
  float sa = v0+v1, sb = v0*v0+v1*v1;
  reduce2(sa, sb, scr);
  float mean = sa*(1.f/512.f);
  float var = sb*(1.f/512.f) - mean*mean;
  float inv = rsqrtf(var + 1e-5f);
  const float* prow = pos + (size_t)(s-1)*DD;
  float r0 = (v0-mean)*inv*lw[tid]     + lb[tid]     + prow[tid];
  float r1 = (v1-mean)*inv*lw[tid+256] + lb[tid+256] + prow[tid+256];
  h16[(size_t)row*DD+tid]=f2b(r0); h16[(size_t)row*DD+tid+256]=f2b(r1);
}

// ---------------- attn merge: conv + LN(aln) + LN(n1) ----------------
__global__ void attn_merge(const u16* __restrict__ h, const u16* __restrict__ ga,
                           const float* __restrict__ cw, const float* __restrict__ cb,
                           const float* __restrict__ aw, const float* __restrict__ ab,
                           const float* __restrict__ nw, const float* __restrict__ nb,
                           u16* __restrict__ o16)
{
  __shared__ float scr[8];
  const int row = blockIdx.x;
  const int s = row % S1;
  const int tid = threadIdx.x;
  float hv[2], vv[2];
  #pragma unroll
  for (int e=0;e<2;e++) {
    const int d = tid + e*256;
    const float hc = b2f(h[(size_t)row*DD+d]);
    const float hm = (s>0)    ? b2f(h[(size_t)(row-1)*DD+d]) : 0.f;
    const float hp = (s<S1-1) ? b2f(h[(size_t)(row+1)*DD+d]) : 0.f;
    const float la = cw[d*3]*hm + cw[d*3+1]*hc + cw[d*3+2]*hp + cb[d];
    hv[e] = hc;
    vv[e] = hc + b2f(ga[(size_t)row*DD+d]) + 0.3f*la;
  }
  float sa = vv[0]+vv[1], sb = vv[0]*vv[0]+vv[1]*vv[1];
  reduce2(sa,sb,scr);
  float mean = sa*(1.f/512.f), var = sb*(1.f/512.f)-mean*mean;
  float inv = rsqrtf(var+1e-5f);
  float u0 = hv[0] + ((vv[0]-mean)*inv*aw[tid]     + ab[tid]);
  float u1 = hv[1] + ((vv[1]-mean)*inv*aw[tid+256] + ab[tid+256]);
  sa = u0+u1; sb = u0*u0+u1*u1;
  reduce2(sa,sb,scr);
  mean = sa*(1.f/512.f); var = sb*(1.f/512.f)-mean*mean;
  inv = rsqrtf(var+1e-5f);
  float r0 = (u0-mean)*inv*nw[tid]+nb[tid];
  float r1 = (u1-mean)*inv*nw[tid+256]+nb[tid+256];
  o16[(size_t)row*DD+tid]=f2b(r0); o16[(size_t)row*DD+tid+256]=f2b(r1);
}

// ---------------- h = LN(h + f*gate) ----------------
__global__ void resid_ln(const u16* __restrict__ h, const u16* __restrict__ fg,
                         const float* __restrict__ nw, const float* __restrict__ nb,
                         u16* __restrict__ o16)
{
  __shared__ float scr[8];
  const int row = blockIdx.x;
  const int tid = threadIdx.x;
  float u0 = b2f(h[(size_t)row*DD+tid])     + b2f(fg[(size_t)row*DD+tid]);
  float u1 = b2f(h[(size_t)row*DD+tid+256]) + b2f(fg[(size_t)row*DD+tid+256]);
  float sa = u0+u1, sb = u0*u0+u1*u1;
  reduce2(sa,sb,scr);
  float mean = sa*(1.f/512.f), var = sb*(1.f/512.f)-mean*mean;
  float inv = rsqrtf(var+1e-5f);
  float r0 = (u0-mean)*inv*nw[tid]+nb[tid];
  float r1 = (u1-mean)*inv*nw[tid+256]+nb[tid+256];
  o16[(size_t)row*DD+tid]=f2b(r0); o16[(size_t)row*DD+tid+256]=f2b(r1);
}

// ---------------- compact xs = h[:,1:,:] (bf16) ----------------
__global__ void xs_compact(const u16* __restrict__ h16, u16* __restrict__ xs)
{
  const size_t idx = (size_t)blockIdx.x*256 + threadIdx.x;   // chunk of 8
  const size_t row = idx >> 6;
  const int ch = (int)(idx & 63);
  const int b = (int)(row / SS), s = (int)(row % SS);
  *(short8*)(xs + row*DD + ch*8) =
      *(const short8*)(h16 + ((size_t)b*S1 + 1 + s)*DD + ch*8);
}

// ---------------- pool attention (PH=4, pdk=128, 448 keys), fp32 softmax ----------------
__global__ void pool_attn(const float* __restrict__ qv, const u16* __restrict__ kp,
                          const u16* __restrict__ vp, u16* __restrict__ po)
{
  __shared__ float sc[448];
  __shared__ float scr[8];
  __shared__ float red[256];
  const int blk = blockIdx.x;
  const int b = blk >> 2, ph = blk & 3;
  const int tid = threadIdx.x;
  float s[2] = {-3e30f, -3e30f};
  #pragma unroll
  for (int it=0; it<2; it++) {
    const int key = tid + it*256;
    if (key < 448) {
      const u16* kr = kp + ((size_t)b*SS + key)*DD + ph*128;
      float acc = 0.f;
      for (int d=0; d<128; d+=8) {
        short8 k8 = *(const short8*)(kr + d);
        #pragma unroll
        for (int i=0;i<8;i++) acc += qv[ph*128+d+i]*b2f((u16)k8[i]);
      }
      s[it] = acc * 0.088388347648318447f;
    }
  }
  float mx = fmaxf(s[0], s[1]);
  #pragma unroll
  for (int off=1; off<64; off<<=1) mx = fmaxf(mx, __shfl_xor(mx, off));
  const int w = tid>>6;
  __syncthreads();
  if ((tid&63)==0) scr[w] = mx;
  __syncthreads();
  mx = fmaxf(fmaxf(scr[0],scr[1]), fmaxf(scr[2],scr[3]));
  float ps = 0.f;
  #pragma unroll
  for (int it=0;it<2;it++){
    const int key = tid+it*256;
    if (key<448) { float p = __expf(s[it]-mx); sc[key]=p; ps += p; }
  }
  #pragma unroll
  for (int off=1; off<64; off<<=1) ps += __shfl_xor(ps, off);
  __syncthreads();
  if ((tid&63)==0) scr[4+w] = ps;
  __syncthreads();
  const float lsum = scr[4]+scr[5]+scr[6]+scr[7];
  const int d = tid & 127, half = tid >> 7;
  float acc = 0.f;
  for (int key = half*224; key < half*224+224; key++)
    acc += sc[key] * b2f(vp[((size_t)b*SS+key)*DD + ph*128 + d]);
  red[tid] = acc;
  __syncthreads();
  if (tid < 128) po[(size_t)b*DD + ph*128 + tid] = f2b((red[tid]+red[tid+128])/lsum);
}

// ---------------- comb = [cls_out | LN(po2, pln)] ----------------
__global__ void comb_build(const u16* __restrict__ hfin, const float* __restrict__ po2,
                           const float* __restrict__ plw, const float* __restrict__ plb,
                           float* __restrict__ c32, u16* __restrict__ c16)
{
  __shared__ float scr[8];
  const int b = blockIdx.x, tid = threadIdx.x;
  #pragma unroll
  for (int e=0;e<2;e++) {
    const int d = tid+e*256;
    const float v = b2f(hfin[((size_t)b*S1)*DD + d]);
    c32[(size_t)b*1024+d] = v; c16[(size_t)b*1024+d] = f2b(v);
  }
  const float* x = po2 + (size_t)b*DD;
  float v0=x[tid], v1=x[tid+256];
  float sa=v0+v1, sb=v0*v0+v1*v1;
  reduce2(sa,sb,scr);
  float mean=sa*(1.f/512.f), var=sb*(1.f/512.f)-mean*mean;
  float inv=rsqrtf(var+1e-5f);
  float r0=(v0-mean)*inv*plw[tid]+plb[tid];
  float r1=(v1-mean)*inv*plw[tid+256]+plb[tid+256];
  c32[(size_t)b*1024+512+tid]=r0; c32[(size_t)b*1024+512+tid+256]=r1;
  c16[(size_t)b*1024+512+tid]=f2b(r0); c16[(size_t)b*1024+512+tid+256]=f2b(r1);
}

// ---------------- per-head LN over 1024 (rows = T*B) ----------------
__global__ void head_ln(const float* __restrict__ c32, const float* __restrict__ lw,
                        const float* __restrict__ lb, u16* __restrict__ out)
{
  __shared__ float scr[8];
  const int r = blockIdx.x;
  const int t = r / 64, b = r % 64;
  const int tid = threadIdx.x;
  const float* x = c32 + (size_t)b*1024;
  float v[4]; float sa=0.f, sb=0.f;
  #pragma unroll
  for (int e=0;e<4;e++){ v[e]=x[tid+e*256]; sa+=v[e]; sb+=v[e]*v[e]; }
  reduce2(sa,sb,scr);
  float mean=sa*(1.f/1024.f), var=sb*(1.f/1024.f)-mean*mean;
  float inv=rsqrtf(var+1e-5f);
  #pragma unroll
  for (int e=0;e<4;e++){
    const int d = tid+e*256;
    out[(size_t)r*1024+d] = f2b((v[e]-mean)*inv*lw[t*1024+d] + lb[t*1024+d]);
  }
}

// ---------------- one wave per output element dot-product GEMM ----------------
template<int ACT, int OUTBF>
__launch_bounds__(256)
__global__ void wavedot(const u16* __restrict__ A, int K, int aMod,
                        const u16* __restrict__ Wt,
                        const float* __restrict__ bias,
                        void* __restrict__ out, int N, int rows, int rowsPerT)
{
  const int gw = (int)(((size_t)blockIdx.x*256 + threadIdx.x) >> 6);
  const int lane = threadIdx.x & 63;
  if (gw >= rows*N) return;
  const int row = gw / N, col = gw % N;
  const int t = row / rowsPerT;
  const int arow = row % aMod;
  const u16* a  = A + (size_t)arow*K;
  const u16* wv = Wt + ((size_t)t*N + col)*K;
  float acc = 0.f;
  for (int k = lane*8; k < K; k += 512) {
    short8 a8 = *(const short8*)(a+k);
    short8 w8 = *(const short8*)(wv+k);
    #pragma unroll
    for (int i=0;i<8;i++) acc += b2f((u16)a8[i]) * b2f((u16)w8[i]);
  }
  #pragma unroll
  for (int off=1; off<64; off<<=1) acc += __shfl_xor(acc, off);
  if (lane == 0) {
    float v = acc + bias[t*N + col];
    if (ACT==1) v = gelu_f(v);
    if (ACT==2) v = fmaxf(v, 0.f);
    if (OUTBF) ((u16*)out)[(size_t)row*N+col] = f2b(v);
    else       ((float*)out)[(size_t)row*N+col] = v;
  }
}

// ---------------- final logits: (t,b,c) dot over 256, fp32 ----------------
__global__ void logits_k(const float* __restrict__ hh3, const float* __restrict__ w4,
                         const float* __restrict__ b4, float* __restrict__ out)
{
  const int e = blockIdx.x*256 + threadIdx.x;
  if (e >= 576) return;
  const int t = e / 192;
  const int rem = e % 192;
  const int b = rem / 3, c = rem % 3;
  const float* a = hh3 + (size_t)(t*64 + b)*256;
  const float* w = w4 + (size_t)t*256*3 + c;
  float acc = b4[t*3+c];
  for (int k=0;k<256;k++) acc += a[k]*w[k*3];
  out[(size_t)(b*3 + t)*3 + c] = acc;
}

// ---------------- uncertainty head: dot 256 + softplus, fp32 ----------------
__global__ void u2_k(const float* __restrict__ uu, const float* __restrict__ w2,
                     const float* __restrict__ b2, float* __restrict__ out)
{
  const int e = blockIdx.x*256 + threadIdx.x;
  if (e >= 192) return;
  const int t = e / 64, b = e % 64;
  const float* a = uu + (size_t)e*256;
  const float* w = w2 + (size_t)t*256;
  float acc = b2[t];
  for (int k=0;k<256;k++) acc += a[k]*w[k];
  acc = (acc > 30.f) ? acc : log1pf(expf(acc));
  out[576 + b*3 + t] = acc;
}

extern "C" void kernel_launch(void* const* d_in, const int* in_sizes, int n_in,
                              void* d_out, int out_size, void* d_ws, size_t ws_size,
                              hipStream_t stream)
{
  const float* x      = (const float*)d_in[0];
  const float* in_w1  = (const float*)d_in[1];
  const float* in_b1  = (const float*)d_in[2];
  const float* in_w2  = (const float*)d_in[3];
  const float* in_b2  = (const float*)d_in[4];
  const float* in_lnw = (const float*)d_in[5];
  const float* in_lnb = (const float*)d_in[6];
  const float* pos    = (const float*)d_in[7];
  const float* cls    = (const float*)d_in[8];
  const float* wq     = (const float*)d_in[9];
  const float* bq     = (const float*)d_in[10];
  const float* wk     = (const float*)d_in[11];
  const float* bk     = (const float*)d_in[12];
  const float* wv     = (const float*)d_in[13];
  const float* bv     = (const float*)d_in[14];
  const float* wo     = (const float*)d_in[15];
  const float* bo     = (const float*)d_in[16];
  const float* conv_w = (const float*)d_in[17];
  const float* conv_b = (const float*)d_in[18];
  const float* aln_w  = (const float*)d_in[19];
  const float* aln_b  = (const float*)d_in[20];
  const float* f_w1   = (const float*)d_in[21];
  const float* f_b1   = (const float*)d_in[22];
  const float* f_w2   = (const float*)d_in[23];
  const float* f_b2   = (const float*)d_in[24];
  const float* f_w3   = (const float*)d_in[25];
  const float* f_b3   = (const float*)d_in[26];
  const float* g_w    = (const float*)d_in[27];
  const float* g_b    = (const float*)d_in[28];
  const float* n1_w   = (const float*)d_in[29];
  const float* n1_b   = (const float*)d_in[30];
  const float* n2_w   = (const float*)d_in[31];
  const float* n2_b   = (const float*)d_in[32];
  const float* pqv    = (const float*)d_in[33];
  const float* pqw    = (const float*)d_in[34];
  const float* pqb    = (const float*)d_in[35];
  const float* pkw    = (const float*)d_in[36];
  const float* pkb    = (const float*)d_in[37];
  const float* pvw    = (const float*)d_in[38];
  const float* pvb    = (const float*)d_in[39];
  const float* pow_w  = (const float*)d_in[40];
  const float* pow_b  = (const float*)d_in[41];
  const float* pln_w  = (const float*)d_in[42];
  const float* pln_b  = (const float*)d_in[43];
  const float* h_lnw  = (const float*)d_in[44];
  const float* h_lnb  = (const float*)d_in[45];
  const float* h_w1   = (const float*)d_in[46];
  const float* h_b1   = (const float*)d_in[47];
  const float* h_w2   = (const float*)d_in[48];
  const float* h_b2   = (const float*)d_in[49];
  const float* h_w3   = (const float*)d_in[50];
  const float* h_b3   = (const float*)d_in[51];
  const float* h_w4   = (const float*)d_in[52];
  const float* h_b4   = (const float*)d_in[53];
  const float* u_w1   = (const float*)d_in[54];
  const float* u_b1   = (const float*)d_in[55];
  const float* u_w2   = (const float*)d_in[56];
  const float* u_b2   = (const float*)d_in[57];
  float* out = (float*)d_out;

  char* wsp = (char*)d_ws;
  size_t off = 0;
  auto alloc = [&](size_t bytes) -> char* {
    char* p = wsp + off;
    off += (bytes + 255) & ~(size_t)255;
    return p;
  };

  // ---- bf16 transposed weights (persistent across the call) ----
  u16* w_in1T = (u16*)alloc((size_t)256*128*2);
  u16* w_in2T = (u16*)alloc((size_t)512*256*2);
  u16* wqT  = (u16*)alloc((size_t)LL*512*512*2);
  u16* wkT  = (u16*)alloc((size_t)LL*512*512*2);
  u16* wvT  = (u16*)alloc((size_t)LL*512*512*2);
  u16* woT  = (u16*)alloc((size_t)LL*512*512*2);
  u16* gwT  = (u16*)alloc((size_t)LL*512*512*2);
  // per-layer FFN weight buffers (reconverted each layer)
  u16* fw1T = (u16*)alloc((size_t)3072*512*2);
  u16* fw2T = (u16*)alloc((size_t)3072*3072*2);
  u16* fw3T = (u16*)alloc((size_t)512*3072*2);
  u16* pkwT = (u16*)alloc((size_t)512*512*2);
  u16* pvwT = (u16*)alloc((size_t)512*512*2);
  u16* powT = (u16*)alloc((size_t)512*512*2);
  u16* pqwT = (u16*)alloc((size_t)512*512*2);
  u16* hw1T = (u16*)alloc((size_t)TT*1024*1024*2);
  u16* hw2T = (u16*)alloc((size_t)TT*512*1024*2);
  u16* hw3T = (u16*)alloc((size_t)TT*256*512*2);
  u16* uw1T = (u16*)alloc((size_t)TT*256*1024*2);

  // ---- activations (bf16, aggressively aliased; lifetimes audited) ----
  u16* hA16 = (u16*)alloc((size_t)N1P*DD*2);   // residual stream (post-LN h)
  u16* hB16 = (u16*)alloc((size_t)N1P*DD*2);   // post-n1 stream; ALSO flash ctx out
  u16* q16  = (u16*)alloc((size_t)N1P*DD*2);   // q; ALSO gate; ALSO xs (pool)
  u16* k16  = (u16*)alloc((size_t)N1P*DD*2);   // k; ALSO attn-out/t2/ffn-out (tmpa); pool-K
  u16* v16  = (u16*)alloc((size_t)N1P*DD*2);   // v; pool-V
  u16* fbuf1 = (u16*)alloc((size_t)FBROWS*FF*2);  // FFN chunk buf; input x16 aliased inside
  u16* fbuf2 = (u16*)alloc((size_t)FBROWS*FF*2);  // FFN chunk buf; input t1b aliased inside
  u16* ctx16  = hB16;
  u16* tmpa16 = k16;
  u16* gate16 = q16;
  u16* x16 = fbuf1;   // NS*128 elems << FBROWS*FF
  u16* t1b = fbuf2;   // NS*256 elems << FBROWS*FF
  // small tails
  u16* pq16   = (u16*)alloc(512*2);
  float* qvec = (float*)alloc(512*4);
  u16* po16   = (u16*)alloc((size_t)64*512*2);
  float* po2  = (float*)alloc((size_t)64*512*4);
  float* comb32 = (float*)alloc((size_t)64*1024*4);
  u16*   comb16 = (u16*)alloc((size_t)64*1024*2);
  u16* hh0 = (u16*)alloc((size_t)192*1024*2);
  u16* hh1 = (u16*)alloc((size_t)192*1024*2);
  u16* hh2 = (u16*)alloc((size_t)192*512*2);
  float* hh3 = (float*)alloc((size_t)192*256*4);
  float* uu  = (float*)alloc((size_t)192*256*4);
  (void)ws_size;

  const dim3 tb(32,8);
  transcvt<<<dim3(4,8,1),   tb, 0, stream>>>(in_w1, w_in1T, 128, 256);
  transcvt<<<dim3(8,16,1),  tb, 0, stream>>>(in_w2, w_in2T, 256, 512);
  transcvt<<<dim3(16,16,LL),tb, 0, stream>>>(wq,  wqT, 512, 512);
  transcvt<<<dim3(16,16,LL),tb, 0, stream>>>(wk,  wkT, 512, 512);
  transcvt<<<dim3(16,16,LL),tb, 0, stream>>>(wv,  wvT, 512, 512);
  transcvt<<<dim3(16,16,LL),tb, 0, stream>>>(wo,  woT, 512, 512);
  transcvt<<<dim3(16,16,LL),tb, 0, stream>>>(g_w, gwT, 512, 512);
  transcvt<<<dim3(16,16,1), tb, 0, stream>>>(pkw,   pkwT, 512, 512);
  transcvt<<<dim3(16,16,1), tb, 0, stream>>>(pvw,   pvwT, 512, 512);
  transcvt<<<dim3(16,16,1), tb, 0, stream>>>(pow_w, powT, 512, 512);
  transcvt<<<dim3(16,16,1), tb, 0, stream>>>(pqw,   pqwT, 512, 512);
  transcvt<<<dim3(32,32,TT),tb, 0, stream>>>(h_w1, hw1T, 1024, 1024);
  transcvt<<<dim3(32,16,TT),tb, 0, stream>>>(h_w2, hw2T, 1024, 512);
  transcvt<<<dim3(16,8,TT), tb, 0, stream>>>(h_w3, hw3T, 512, 256);
  transcvt<<<dim3(32,8,TT), tb, 0, stream>>>(u_w1, uw1T, 1024, 256);

  cvt<<<(NS*128+255)/256, 256, 0, stream>>>(x,  x16,  NS*128);
  cvt<<<2, 256, 0, stream>>>(pqv, pq16, 512);

  // input MLP (writes t2 into tmpa16 == k16)
  gemm128<1,0><<<dim3(224,2),256,0,stream>>>(x16,128, w_in1T,128, in_b1, t1b,256, nullptr, 128);
  gemm128<0,0><<<dim3(224,4),256,0,stream>>>(t1b,256, w_in2T,256, in_b2, tmpa16,512, nullptr, 256);
  ln_pos_cls<<<N1,256,0,stream>>>(tmpa16, in_lnw, in_lnb, pos, cls, hA16);

  static const int CH_T[8] = {29,28,28,28,28,28,28,28};

  for (int i=0;i<LL;i++){
    const size_t wOff = (size_t)i*512*512;
    // per-layer FFN weight conversion (overlaps with attention phase on the stream)
    transcvt<<<dim3(16,96,1),tb,0,stream>>>(f_w1 + (size_t)i*512*3072,  fw1T, 512, 3072);
    transcvt<<<dim3(96,96,1),tb,0,stream>>>(f_w2 + (size_t)i*3072*3072, fw2T, 3072, 3072);
    transcvt<<<dim3(96,16,1),tb,0,stream>>>(f_w3 + (size_t)i*3072*512,  fw3T, 3072, 512);

    gemm128<0,0><<<dim3(225,4),256,0,stream>>>(hA16,512, wqT+wOff,512, bq+i*512, q16,512, nullptr, 512);
    gemm128<0,0><<<dim3(225,4),256,0,stream>>>(hA16,512, wkT+wOff,512, bk+i*512, k16,512, nullptr, 512);
    gemm128<0,0><<<dim3(225,4),256,0,stream>>>(hA16,512, wvT+wOff,512, bv+i*512, v16,512, nullptr, 512);
    flash_attn<<<4096,256,0,stream>>>(q16,k16,v16,ctx16);
    gemm128<0,0><<<dim3(225,4),256,0,stream>>>(ctx16,512, woT+wOff,512, bo+i*512, tmpa16,512, nullptr, 512);
    attn_merge<<<N1,256,0,stream>>>(hA16, tmpa16, conv_w+(size_t)i*1536, conv_b+i*512,
                                    aln_w+i*512, aln_b+i*512, n1_w+i*512, n1_b+i*512, hB16);
    gemm128<2,0><<<dim3(225,4),256,0,stream>>>(hB16,512, gwT+wOff,512, g_b+i*512, gate16,512, nullptr, 512);
    // chunked FFN (keeps fbuf footprint small)
    int t0 = 0;
    for (int c=0;c<8;c++){
      const int nt = CH_T[c];
      const size_t r0 = (size_t)t0*128;
      gemm128<1,0><<<dim3(nt,24),256,0,stream>>>(hB16 + r0*512, 512, fw1T, 512, f_b1+i*3072, fbuf1, 3072, nullptr, 512);
      gemm128<1,0><<<dim3(nt,24),256,0,stream>>>(fbuf1, 3072, fw2T, 3072, f_b2+i*3072, fbuf2, 3072, nullptr, 3072);
      gemm128<0,1><<<dim3(nt,4), 256,0,stream>>>(fbuf2, 3072, fw3T, 3072, f_b3+i*512, tmpa16 + r0*512, 512, gate16 + r0*512, 3072);
      t0 += nt;
    }
    resid_ln<<<N1,256,0,stream>>>(hB16, tmpa16, n2_w+i*512, n2_b+i*512, hA16);
  }

  // pooling attention
  xs_compact<<<NS*64/256,256,0,stream>>>(hA16, q16);
  gemm128<0,0><<<dim3(224,4),256,0,stream>>>(q16,512, pkwT,512, pkb, k16,512, nullptr, 512);
  gemm128<0,0><<<dim3(224,4),256,0,stream>>>(q16,512, pvwT,512, pvb, v16,512, nullptr, 512);
  wavedot<0,0><<<128,256,0,stream>>>(pq16, 512, 1, pqwT, pqb, qvec, 512, 1, 1);
  pool_attn<<<256,256,0,stream>>>(qvec, k16, v16, po16);
  wavedot<0,0><<<8192,256,0,stream>>>(po16, 512, 64, powT, pow_b, po2, 512, 64, 64);
  comb_build<<<64,256,0,stream>>>(hA16, po2, pln_w, pln_b, comb32, comb16);

  // heads
  head_ln<<<192,256,0,stream>>>(comb32, h_lnw, h_lnb, hh0);
  wavedot<1,1><<<49152,256,0,stream>>>(hh0, 1024, 192, hw1T, h_b1, hh1, 1024, 192, 64);
  wavedot<1,1><<<24576,256,0,stream>>>(hh1, 1024, 192, hw2T, h_b2, hh2, 512, 192, 64);
  wavedot<1,0><<<12288,256,0,stream>>>(hh2, 512, 192, hw3T, h_b3, hh3, 256, 192, 64);
  logits_k<<<3,256,0,stream>>>(hh3, h_w4, h_b4, out);
  wavedot<2,0><<<12288,256,0,stream>>>(comb16, 1024, 64, uw1T, u_b1, uu, 256, 192, 64);
  u2_k<<<1,256,0,stream>>>(uu, u_w2, u_b2, out);
}

// Round 3
// 10430.315 us; speedup vs baseline: 1.2329x; 1.2329x over previous
//
#include <hip/hip_runtime.h>

#define BB 64
#define SS 448
#define S1 449
#define DD 512
#define HH 8
#define LL 6
#define TT 3
#define FF 3072
#define NS 28672
#define N1 28736
#define N1P 28800
#define FB1 ((size_t)3712*3072)   // fbuf1 elems (29*128 rows x 3072)

typedef unsigned short u16;
typedef __attribute__((ext_vector_type(8))) short short8;
typedef __attribute__((ext_vector_type(4))) float floatx4;

#define AS1C(p) ((const __attribute__((address_space(1))) void*)(p))
#define AS3P(p) ((__attribute__((address_space(3))) void*)(p))

__device__ __forceinline__ float b2f(u16 u){
  union { float f; unsigned u; } x; x.u = ((unsigned)u) << 16; return x.f;
}
__device__ __forceinline__ u16 f2b(float f){
  union { float f; unsigned u; } x; x.f = f;
  unsigned r = x.u + 0x7FFFu + ((x.u >> 16) & 1u);
  return (u16)(r >> 16);
}
__device__ __forceinline__ float gelu_f(float v){ return 0.5f*v*(1.f+erff(v*0.70710678118654752440f)); }
__device__ __forceinline__ float sigm_f(float v){ return 1.f/(1.f+expf(-v)); }

__device__ __forceinline__ void reduce2(float& a, float& b, float* scr){
  #pragma unroll
  for (int off=1; off<64; off<<=1){ a += __shfl_xor(a, off); b += __shfl_xor(b, off); }
  const int w = threadIdx.x >> 6;
  __syncthreads();
  if ((threadIdx.x & 63) == 0){ scr[w] = a; scr[4+w] = b; }
  __syncthreads();
  a = scr[0]+scr[1]+scr[2]+scr[3];
  b = scr[4]+scr[5]+scr[6]+scr[7];
}

// ---------------- transpose + fp32->bf16: dst[n][k] = src[k][n]; z strides separate ----------------
__global__ void transcvt(const float* __restrict__ src, u16* __restrict__ dst, int K, int N, size_t dls){
  __shared__ float t[32][33];
  src += (size_t)blockIdx.z * K * N;
  dst += (size_t)blockIdx.z * dls;
  const int k0 = blockIdx.x*32, n0 = blockIdx.y*32;
  const int tx = threadIdx.x, ty = threadIdx.y;
  #pragma unroll
  for (int i=0;i<32;i+=8) t[ty+i][tx] = src[(size_t)(k0+ty+i)*N + n0+tx];
  __syncthreads();
  #pragma unroll
  for (int i=0;i<32;i+=8) dst[(size_t)(n0+ty+i)*K + k0+tx] = f2b(t[tx][ty+i]);
}

__global__ void cvt(const float* __restrict__ src, u16* __restrict__ dst, int n){
  int i = blockIdx.x*256 + threadIdx.x;
  if (i < n) dst[i] = f2b(src[i]);
}

__global__ void biascat(const float* __restrict__ a, const float* __restrict__ b, float* __restrict__ dst){
  int i = blockIdx.x*256 + threadIdx.x;
  if (i >= LL*1024) return;
  int l = i >> 10, c = i & 1023;
  dst[i] = (c < 512) ? a[l*512 + c] : b[l*512 + (c-512)];
}

// ---------------- bf16 MFMA GEMM: C[M,N] = act(A @ Bt^T + bias) [* mul] ----------------
// 128x128 tile, BK=32. TSEL: M-tile index selects weight block t (Bt += t*N*K, bias += t*N).
template<int ACT, int HASMUL, int TSEL>
__launch_bounds__(256)
__global__ void gemm128(const u16* __restrict__ A, int lda,
                        const u16* __restrict__ Bt, int ldb,
                        const float* __restrict__ bias,
                        u16* __restrict__ Cp, int ldc,
                        const u16* __restrict__ mulp,
                        int K)
{
  __shared__ u16 Al[4096];
  __shared__ u16 Bl[4096];
  const int tid = threadIdx.x;
  const int lane = tid & 63;
  const int w = tid >> 6;
  const int wm = (w >> 1) * 64;
  const int wn = (w & 1) * 64;
  const size_t m0 = (size_t)blockIdx.x * 128;
  const size_t n0 = (size_t)blockIdx.y * 128;
  if (TSEL) {
    const int N = gridDim.y * 128;
    Bt  += (size_t)blockIdx.x * N * ldb;
    bias += (size_t)blockIdx.x * N;
  }

  const int c1 = 256 + tid;
  const u16* a0 = A + (m0 + (tid>>2))*lda + (tid&3)*8;
  const u16* a1 = A + (m0 + (c1>>2))*lda + (c1&3)*8;
  const u16* b0 = Bt + ((TSEL?0:n0) + (tid>>2))*ldb + (tid&3)*8;
  const u16* b1 = Bt + ((TSEL?0:n0) + (c1>>2))*ldb + (c1&3)*8;
  if (TSEL) { b0 += n0*ldb; b1 += n0*ldb; }

  const floatx4 fz = {0.f,0.f,0.f,0.f};
  floatx4 acc[4][4];
  #pragma unroll
  for (int i=0;i<4;i++)
    #pragma unroll
    for (int j=0;j<4;j++) acc[i][j] = fz;

  const int fr = lane & 15;
  const int fq = (lane >> 4) * 8;

  for (int k0 = 0; k0 < K; k0 += 32) {
    __syncthreads();
    __builtin_amdgcn_global_load_lds(AS1C(a0), AS3P(Al + w*512),        16, 0, 0);
    __builtin_amdgcn_global_load_lds(AS1C(a1), AS3P(Al + 2048 + w*512), 16, 0, 0);
    __builtin_amdgcn_global_load_lds(AS1C(b0), AS3P(Bl + w*512),        16, 0, 0);
    __builtin_amdgcn_global_load_lds(AS1C(b1), AS3P(Bl + 2048 + w*512), 16, 0, 0);
    a0 += 32; a1 += 32; b0 += 32; b1 += 32;
    __syncthreads();
    short8 af[4], bf[4];
    #pragma unroll
    for (int i=0;i<4;i++) af[i] = *(const short8*)(Al + (wm + i*16 + fr)*32 + fq);
    #pragma unroll
    for (int j=0;j<4;j++) bf[j] = *(const short8*)(Bl + (wn + j*16 + fr)*32 + fq);
    #pragma unroll
    for (int i=0;i<4;i++)
      #pragma unroll
      for (int j=0;j<4;j++)
        acc[i][j] = __builtin_amdgcn_mfma_f32_16x16x32_bf16(af[i], bf[j], acc[i][j], 0, 0, 0);
  }

  const int cr = (lane >> 4) * 4;
  const int cc = lane & 15;
  #pragma unroll
  for (int i=0;i<4;i++) {
    #pragma unroll
    for (int j=0;j<4;j++) {
      const size_t gc = n0 + wn + j*16 + cc;
      const float bv = bias[gc - (TSEL ? 0 : 0)];
      #pragma unroll
      for (int r=0;r<4;r++) {
        const size_t gr = m0 + wm + i*16 + cr + r;
        float vv = acc[i][j][r] + bv;
        if (ACT==1) vv = gelu_f(vv);
        if (ACT==2) vv = sigm_f(vv);
        if (ACT==3) vv = fmaxf(vv, 0.f);
        if (HASMUL) vv *= b2f(mulp[gr*ldc + gc]);
        Cp[gr*ldc + gc] = f2b(vv);
      }
    }
  }
}

// ---------------- V transpose per layer: vT[b][h][d(64)][key(512pad)] ----------------
__global__ void vtrans(const u16* __restrict__ v, u16* __restrict__ vT){
  __shared__ u16 t[32][72];
  const int bh = blockIdx.y;
  const int b = bh >> 3, h = bh & 7;
  const int k0 = blockIdx.x * 32;
  const int tid = threadIdx.x;
  {
    const int key = tid >> 3, dch = tid & 7;
    const int ka = k0 + key;
    short8 val = {0,0,0,0,0,0,0,0};
    if (ka < S1) val = *(const short8*)(v + ((size_t)b*S1 + ka)*DD + h*64 + dch*8);
    *(short8*)(&t[key][dch*8]) = val;
  }
  __syncthreads();
  const int d = tid >> 2, kk = tid & 3;
  short8 o;
  #pragma unroll
  for (int i=0;i<8;i++) o[i] = (short)t[kk*8+i][d];
  *(short8*)(vT + ((size_t)bh*64 + d)*512 + k0 + kk*8) = o;
}

// ---------------- flash attention (bf16 MFMA, fp32 softmax, swizzled LDS staging) ----------------
__launch_bounds__(256)
__global__ void flash_attn(const u16* __restrict__ qkg,   // [N1P,1024]: q | k
                           const u16* __restrict__ vT,    // [B*H, 64, 512]
                           u16* __restrict__ ctx)         // [N1P,512]
{
  const int bid = blockIdx.x;
  const int qt = bid & 7;
  const int h  = (bid >> 3) & 7;
  const int b  = bid >> 6;
  const int tid = threadIdx.x;
  const int lane = tid & 63;
  const int w = tid >> 6;

  __shared__ u16 Kl[2048];      // 32 keys x 64 d, 16B-unit xor swizzle
  __shared__ u16 Vl[2048];      // 64 d x 32 keys, 16B-unit xor swizzle
  __shared__ u16 Pl[4][16*40];  // per-wave P scratch, stride 40

  const int fr = lane & 15;
  const int q4 = lane >> 4;
  const int fq = q4 * 8;

  const int qrow = qt*64 + w*16;
  const size_t qoff = ((size_t)b*S1 + qrow + fr)*1024 + h*64 + fq;
  const short8 qf0 = *(const short8*)(qkg + qoff);
  const short8 qf1 = *(const short8*)(qkg + qoff + 32);

  const floatx4 fz = {0.f,0.f,0.f,0.f};
  floatx4 oacc[4] = {fz, fz, fz, fz};
  float mm[4] = {-3e30f,-3e30f,-3e30f,-3e30f};
  float ll[4] = {0.f,0.f,0.f,0.f};

  // K staging: lane covers key tid>>3, swizzled 16B unit (tid&7)^((tid>>3)&7)
  const u16* gk = qkg + ((size_t)b*S1 + (tid>>3))*1024 + 512 + h*64
                + (((tid&7) ^ ((tid>>3)&7)) * 8);
  // V staging from vT: lane covers d = tid>>2, unit (tid&3)^((tid>>2)&3)
  const u16* gv = vT + ((size_t)(b*8+h)*64 + (tid>>2))*512
                + (((tid&3) ^ ((tid>>2)&3)) * 8);

  // swizzled LDS read offsets (elements)
  const int kswz0 = (( q4      ^ (fr&7)) * 8);
  const int kswz1 = (((4+q4)   ^ (fr&7)) * 8);
  const int vswz  = (( q4      ^ (fr&3)) * 8);

  for (int k0 = 0; k0 < 480; k0 += 32) {
    __syncthreads();
    __builtin_amdgcn_global_load_lds(AS1C(gk), AS3P(Kl + w*512), 16, 0, 0);
    __builtin_amdgcn_global_load_lds(AS1C(gv), AS3P(Vl + w*512), 16, 0, 0);
    gk += 32*1024; gv += 32;
    __syncthreads();

    floatx4 s0 = fz, s1 = fz;
    {
      short8 kb0  = *(const short8*)(Kl + fr*64 + kswz0);
      short8 kb0h = *(const short8*)(Kl + fr*64 + kswz1);
      s0 = __builtin_amdgcn_mfma_f32_16x16x32_bf16(qf0, kb0,  s0, 0,0,0);
      s0 = __builtin_amdgcn_mfma_f32_16x16x32_bf16(qf1, kb0h, s0, 0,0,0);
      short8 kb1  = *(const short8*)(Kl + (16+fr)*64 + kswz0);
      short8 kb1h = *(const short8*)(Kl + (16+fr)*64 + kswz1);
      s1 = __builtin_amdgcn_mfma_f32_16x16x32_bf16(qf0, kb1,  s1, 0,0,0);
      s1 = __builtin_amdgcn_mfma_f32_16x16x32_bf16(qf1, kb1h, s1, 0,0,0);
    }
    const bool msk0 = (k0 + fr) >= S1;
    const bool msk1 = (k0 + 16 + fr) >= S1;
    float p0[4], p1[4];
    #pragma unroll
    for (int r=0;r<4;r++) {
      p0[r] = msk0 ? -3e30f : s0[r]*0.125f;
      p1[r] = msk1 ? -3e30f : s1[r]*0.125f;
    }
    #pragma unroll
    for (int r=0;r<4;r++) {
      float t = fmaxf(p0[r], p1[r]);
      t = fmaxf(t, __shfl_xor(t,1)); t = fmaxf(t, __shfl_xor(t,2));
      t = fmaxf(t, __shfl_xor(t,4)); t = fmaxf(t, __shfl_xor(t,8));
      float mn = fmaxf(mm[r], t);
      float al = __expf(mm[r]-mn);
      mm[r] = mn;
      float e0 = msk0 ? 0.f : __expf(p0[r]-mn);
      float e1 = msk1 ? 0.f : __expf(p1[r]-mn);
      p0[r]=e0; p1[r]=e1;
      float rs = e0+e1;
      rs += __shfl_xor(rs,1); rs += __shfl_xor(rs,2);
      rs += __shfl_xor(rs,4); rs += __shfl_xor(rs,8);
      ll[r] = ll[r]*al + rs;
      oacc[0][r]*=al; oacc[1][r]*=al; oacc[2][r]*=al; oacc[3][r]*=al;
    }
    const int pr = q4*4;
    #pragma unroll
    for (int r=0;r<4;r++) {
      Pl[w][(pr+r)*40 + fr]      = f2b(p0[r]);
      Pl[w][(pr+r)*40 + 16 + fr] = f2b(p1[r]);
    }
    short8 pf = *(const short8*)(&Pl[w][fr*40 + fq]);
    #pragma unroll
    for (int j=0;j<4;j++) {
      short8 vb = *(const short8*)(Vl + (j*16+fr)*32 + vswz);
      oacc[j] = __builtin_amdgcn_mfma_f32_16x16x32_bf16(pf, vb, oacc[j], 0,0,0);
    }
  }
  const int pr = q4*4;
  #pragma unroll
  for (int r=0;r<4;r++) {
    const int qi = qrow + pr + r;
    if (qi < S1) {
      const size_t base = ((size_t)b*S1 + qi)*DD + h*64 + fr;
      const float inv = 1.f/ll[r];
      ctx[base]    = f2b(oacc[0][r]*inv);
      ctx[base+16] = f2b(oacc[1][r]*inv);
      ctx[base+32] = f2b(oacc[2][r]*inv);
      ctx[base+48] = f2b(oacc[3][r]*inv);
    }
  }
}

// ---------------- input stage: LN + pos + cls ----------------
__global__ void ln_pos_cls(const u16* __restrict__ t2, const float* __restrict__ lw,
                           const float* __restrict__ lb, const float* __restrict__ pos,
                           const float* __restrict__ cls, u16* __restrict__ h16)
{
  __shared__ float scr[8];
  const int row = blockIdx.x;
  const int b = row / S1, s = row % S1;
  const int tid = threadIdx.x;
  if (s == 0) {
    #pragma unroll
    for (int e=0;e<2;e++){ int d = tid + e*256; h16[(size_t)row*DD+d]=f2b(cls[d]); }
    return;
  }
  const u16* x = t2 + ((size_t)b*SS + (s-1))*DD;
  float v0 = b2f(x[tid]), v1 = b2f(x[tid+256]);
  float sa = v0+v1, sb = v0*v0+v1*v1;
  reduce2(sa, sb, scr);
  float mean = sa*(1.f/512.f);
  float var = sb*(1.f/512.f) - mean*mean;
  float inv = rsqrtf(var + 1e-5f);
  const float* prow = pos + (size_t)(s-1)*DD;
  float r0 = (v0-mean)*inv*lw[tid]     + lb[tid]     + prow[tid];
  float r1 = (v1-mean)*inv*lw[tid+256] + lb[tid+256] + prow[tid+256];
  h16[(size_t)row*DD+tid]=f2b(r0); h16[(size_t)row*DD+tid+256]=f2b(r1);
}

// ---------------- attn merge: conv + LN(aln) + LN(n1) ----------------
__global__ void attn_merge(const u16* __restrict__ h, const u16* __restrict__ ga,
                           const float* __restrict__ cw, const float* __restrict__ cb,
                           const float* __restrict__ aw, const float* __restrict__ ab,
                           const float* __restrict__ nw, const float* __restrict__ nb,
                           u16* __restrict__ o16)
{
  __shared__ float scr[8];
  const int row = blockIdx.x;
  const int s = row % S1;
  const int tid = threadIdx.x;
  float hv[2], vv[2];
  #pragma unroll
  for (int e=0;e<2;e++) {
    const int d = tid + e*256;
    const float hc = b2f(h[(size_t)row*DD+d]);
    const float hm = (s>0)    ? b2f(h[(size_t)(row-1)*DD+d]) : 0.f;
    const float hp = (s<S1-1) ? b2f(h[(size_t)(row+1)*DD+d]) : 0.f;
    const float la = cw[d*3]*hm + cw[d*3+1]*hc + cw[d*3+2]*hp + cb[d];
    hv[e] = hc;
    vv[e] = hc + b2f(ga[(size_t)row*DD+d]) + 0.3f*la;
  }
  float sa = vv[0]+vv[1], sb = vv[0]*vv[0]+vv[1]*vv[1];
  reduce2(sa,sb,scr);
  float mean = sa*(1.f/512.f), var = sb*(1.f/512.f)-mean*mean;
  float inv = rsqrtf(var+1e-5f);
  float u0 = hv[0] + ((vv[0]-mean)*inv*aw[tid]     + ab[tid]);
  float u1 = hv[1] + ((vv[1]-mean)*inv*aw[tid+256] + ab[tid+256]);
  sa = u0+u1; sb = u0*u0+u1*u1;
  reduce2(sa,sb,scr);
  mean = sa*(1.f/512.f); var = sb*(1.f/512.f)-mean*mean;
  inv = rsqrtf(var+1e-5f);
  float r0 = (u0-mean)*inv*nw[tid]+nb[tid];
  float r1 = (u1-mean)*inv*nw[tid+256]+nb[tid+256];
  o16[(size_t)row*DD+tid]=f2b(r0); o16[(size_t)row*DD+tid+256]=f2b(r1);
}

// ---------------- h = LN(h + f) ----------------
__global__ void resid_ln(const u16* __restrict__ h, const u16* __restrict__ fg,
                         const float* __restrict__ nw, const float* __restrict__ nb,
                         u16* __restrict__ o16)
{
  __shared__ float scr[8];
  const int row = blockIdx.x;
  const int tid = threadIdx.x;
  float u0 = b2f(h[(size_t)row*DD+tid])     + b2f(fg[(size_t)row*DD+tid]);
  float u1 = b2f(h[(size_t)row*DD+tid+256]) + b2f(fg[(size_t)row*DD+tid+256]);
  float sa = u0+u1, sb = u0*u0+u1*u1;
  reduce2(sa,sb,scr);
  float mean = sa*(1.f/512.f), var = sb*(1.f/512.f)-mean*mean;
  float inv = rsqrtf(var+1e-5f);
  float r0 = (u0-mean)*inv*nw[tid]+nb[tid];
  float r1 = (u1-mean)*inv*nw[tid+256]+nb[tid+256];
  o16[(size_t)row*DD+tid]=f2b(r0); o16[(size_t)row*DD+tid+256]=f2b(r1);
}

// ---------------- xs = h[:,1:,:] ----------------
__global__ void xs_compact(const u16* __restrict__ h16, u16* __restrict__ xs)
{
  const size_t idx = (size_t)blockIdx.x*256 + threadIdx.x;
  const size_t row = idx >> 6;
  const int ch = (int)(idx & 63);
  const int b = (int)(row / SS), s = (int)(row % SS);
  *(short8*)(xs + row*DD + ch*8) =
      *(const short8*)(h16 + ((size_t)b*S1 + 1 + s)*DD + ch*8);
}

// ---------------- pool attention ----------------
__global__ void pool_attn(const float* __restrict__ qv, const u16* __restrict__ kp,
                          const u16* __restrict__ vp, u16* __restrict__ po)
{
  __shared__ float sc[448];
  __shared__ float scr[8];
  __shared__ float red[256];
  const int blk = blockIdx.x;
  const int b = blk >> 2, ph = blk & 3;
  const int tid = threadIdx.x;
  float s[2] = {-3e30f, -3e30f};
  #pragma unroll
  for (int it=0; it<2; it++) {
    const int key = tid + it*256;
    if (key < 448) {
      const u16* kr = kp + ((size_t)b*SS + key)*DD + ph*128;
      float acc = 0.f;
      for (int d=0; d<128; d+=8) {
        short8 k8 = *(const short8*)(kr + d);
        #pragma unroll
        for (int i=0;i<8;i++) acc += qv[ph*128+d+i]*b2f((u16)k8[i]);
      }
      s[it] = acc * 0.088388347648318447f;
    }
  }
  float mx = fmaxf(s[0], s[1]);
  #pragma unroll
  for (int off=1; off<64; off<<=1) mx = fmaxf(mx, __shfl_xor(mx, off));
  const int w = tid>>6;
  __syncthreads();
  if ((tid&63)==0) scr[w] = mx;
  __syncthreads();
  mx = fmaxf(fmaxf(scr[0],scr[1]), fmaxf(scr[2],scr[3]));
  float ps = 0.f;
  #pragma unroll
  for (int it=0;it<2;it++){
    const int key = tid+it*256;
    if (key<448) { float p = __expf(s[it]-mx); sc[key]=p; ps += p; }
  }
  #pragma unroll
  for (int off=1; off<64; off<<=1) ps += __shfl_xor(ps, off);
  __syncthreads();
  if ((tid&63)==0) scr[4+w] = ps;
  __syncthreads();
  const float lsum = scr[4]+scr[5]+scr[6]+scr[7];
  const int d = tid & 127, half = tid >> 7;
  float acc = 0.f;
  for (int key = half*224; key < half*224+224; key++)
    acc += sc[key] * b2f(vp[((size_t)b*SS+key)*DD + ph*128 + d]);
  red[tid] = acc;
  __syncthreads();
  if (tid < 128) po[(size_t)b*DD + ph*128 + tid] = f2b((red[tid]+red[tid+128])/lsum);
}

// ---------------- comb384 rows t*128+b = [cls | LN(po2)] ----------------
__global__ void comb_build(const u16* __restrict__ hfin, const u16* __restrict__ po2,
                           const float* __restrict__ plw, const float* __restrict__ plb,
                           u16* __restrict__ c384)
{
  __shared__ float scr[8];
  const int b = blockIdx.x, tid = threadIdx.x;
  const u16 c0 = hfin[((size_t)b*S1)*DD + tid];
  const u16 c1 = hfin[((size_t)b*S1)*DD + tid + 256];
  float v0 = b2f(po2[(size_t)b*DD + tid]);
  float v1 = b2f(po2[(size_t)b*DD + tid + 256]);
  float sa=v0+v1, sb=v0*v0+v1*v1;
  reduce2(sa,sb,scr);
  float mean=sa*(1.f/512.f), var=sb*(1.f/512.f)-mean*mean;
  float inv=rsqrtf(var+1e-5f);
  u16 r0=f2b((v0-mean)*inv*plw[tid]+plb[tid]);
  u16 r1=f2b((v1-mean)*inv*plw[tid+256]+plb[tid+256]);
  #pragma unroll
  for (int t=0;t<3;t++){
    const size_t base = (size_t)(t*128+b)*1024;
    c384[base+tid]=c0; c384[base+tid+256]=c1;
    c384[base+512+tid]=r0; c384[base+512+tid+256]=r1;
  }
}

// ---------------- head LN over 1024, per t; out rows t*128+b ----------------
__global__ void head_ln(const u16* __restrict__ comb, const float* __restrict__ lw,
                        const float* __restrict__ lb, u16* __restrict__ out)
{
  __shared__ float scr[8];
  const int r = blockIdx.x;
  const int t = r / 64, b = r % 64;
  const int tid = threadIdx.x;
  const u16* x = comb + (size_t)b*1024;
  float v[4]; float sa=0.f, sb=0.f;
  #pragma unroll
  for (int e=0;e<4;e++){ v[e]=b2f(x[tid+e*256]); sa+=v[e]; sb+=v[e]*v[e]; }
  reduce2(sa,sb,scr);
  float mean=sa*(1.f/1024.f), var=sb*(1.f/1024.f)-mean*mean;
  float inv=rsqrtf(var+1e-5f);
  #pragma unroll
  for (int e=0;e<4;e++){
    const int d = tid+e*256;
    out[(size_t)(t*128+b)*1024+d] = f2b((v[e]-mean)*inv*lw[t*1024+d] + lb[t*1024+d]);
  }
}

// ---------------- one-wave dot (small) ----------------
template<int ACT>
__launch_bounds__(256)
__global__ void wavedot(const u16* __restrict__ A, int K,
                        const u16* __restrict__ Wt,
                        const float* __restrict__ bias,
                        float* __restrict__ out, int N)
{
  const int gw = (int)(((size_t)blockIdx.x*256 + threadIdx.x) >> 6);
  const int lane = threadIdx.x & 63;
  if (gw >= N) return;
  const u16* wv = Wt + (size_t)gw*K;
  float acc = 0.f;
  for (int k = lane*8; k < K; k += 512) {
    short8 a8 = *(const short8*)(A+k);
    short8 w8 = *(const short8*)(wv+k);
    #pragma unroll
    for (int i=0;i<8;i++) acc += b2f((u16)a8[i]) * b2f((u16)w8[i]);
  }
  #pragma unroll
  for (int off=1; off<64; off<<=1) acc += __shfl_xor(acc, off);
  if (lane == 0) {
    float v = acc + bias[gw];
    if (ACT==1) v = gelu_f(v);
    out[gw] = v;
  }
}

// ---------------- final logits ----------------
__global__ void logits_k(const u16* __restrict__ hh3, const float* __restrict__ w4,
                         const float* __restrict__ b4, float* __restrict__ out)
{
  const int e = blockIdx.x*256 + threadIdx.x;
  if (e >= 576) return;
  const int t = e / 192;
  const int rem = e % 192;
  const int b = rem / 3, c = rem % 3;
  const u16* a = hh3 + (size_t)(t*128 + b)*256;
  const float* w = w4 + (size_t)t*256*3 + c;
  float acc = b4[t*3+c];
  for (int k=0;k<256;k++) acc += b2f(a[k])*w[k*3];
  out[(size_t)(b*3 + t)*3 + c] = acc;
}

// ---------------- uncertainty head ----------------
__global__ void u2_k(const float* __restrict__ /*unused*/, const u16* __restrict__ uu,
                     const float* __restrict__ w2, const float* __restrict__ b2,
                     float* __restrict__ out)
{
  const int e = blockIdx.x*256 + threadIdx.x;
  if (e >= 192) return;
  const int t = e / 64, b = e % 64;
  const u16* a = uu + (size_t)(t*128 + b)*256;
  const float* w = w2 + (size_t)t*256;
  float acc = b2[t];
  for (int k=0;k<256;k++) acc += b2f(a[k])*w[k];
  acc = (acc > 30.f) ? acc : log1pf(expf(acc));
  out[576 + b*3 + t] = acc;
}

extern "C" void kernel_launch(void* const* d_in, const int* in_sizes, int n_in,
                              void* d_out, int out_size, void* d_ws, size_t ws_size,
                              hipStream_t stream)
{
  const float* x      = (const float*)d_in[0];
  const float* in_w1  = (const float*)d_in[1];
  const float* in_b1  = (const float*)d_in[2];
  const float* in_w2  = (const float*)d_in[3];
  const float* in_b2  = (const float*)d_in[4];
  const float* in_lnw = (const float*)d_in[5];
  const float* in_lnb = (const float*)d_in[6];
  const float* pos    = (const float*)d_in[7];
  const float* cls    = (const float*)d_in[8];
  const float* wq     = (const float*)d_in[9];
  const float* bq     = (const float*)d_in[10];
  const float* wk     = (const float*)d_in[11];
  const float* bk     = (const float*)d_in[12];
  const float* wv     = (const float*)d_in[13];
  const float* bv     = (const float*)d_in[14];
  const float* wo     = (const float*)d_in[15];
  const float* bo     = (const float*)d_in[16];
  const float* conv_w = (const float*)d_in[17];
  const float* conv_b = (const float*)d_in[18];
  const float* aln_w  = (const float*)d_in[19];
  const float* aln_b  = (const float*)d_in[20];
  const float* f_w1   = (const float*)d_in[21];
  const float* f_b1   = (const float*)d_in[22];
  const float* f_w2   = (const float*)d_in[23];
  const float* f_b2   = (const float*)d_in[24];
  const float* f_w3   = (const float*)d_in[25];
  const float* f_b3   = (const float*)d_in[26];
  const float* g_w    = (const float*)d_in[27];
  const float* g_b    = (const float*)d_in[28];
  const float* n1_w   = (const float*)d_in[29];
  const float* n1_b   = (const float*)d_in[30];
  const float* n2_w   = (const float*)d_in[31];
  const float* n2_b   = (const float*)d_in[32];
  const float* pqv    = (const float*)d_in[33];
  const float* pqw    = (const float*)d_in[34];
  const float* pqb    = (const float*)d_in[35];
  const float* pkw    = (const float*)d_in[36];
  const float* pkb    = (const float*)d_in[37];
  const float* pvw    = (const float*)d_in[38];
  const float* pvb    = (const float*)d_in[39];
  const float* pow_w  = (const float*)d_in[40];
  const float* pow_b  = (const float*)d_in[41];
  const float* pln_w  = (const float*)d_in[42];
  const float* pln_b  = (const float*)d_in[43];
  const float* h_lnw  = (const float*)d_in[44];
  const float* h_lnb  = (const float*)d_in[45];
  const float* h_w1   = (const float*)d_in[46];
  const float* h_b1   = (const float*)d_in[47];
  const float* h_w2   = (const float*)d_in[48];
  const float* h_b2   = (const float*)d_in[49];
  const float* h_w3   = (const float*)d_in[50];
  const float* h_b3   = (const float*)d_in[51];
  const float* h_w4   = (const float*)d_in[52];
  const float* h_b4   = (const float*)d_in[53];
  const float* u_w1   = (const float*)d_in[54];
  const float* u_b1   = (const float*)d_in[55];
  const float* u_w2   = (const float*)d_in[56];
  const float* u_b2   = (const float*)d_in[57];
  float* out = (float*)d_out;

  char* wsp = (char*)d_ws;
  size_t off = 0;
  auto alloc = [&](size_t bytes) -> char* {
    char* p = wsp + off;
    off += (bytes + 255) & ~(size_t)255;
    return p;
  };

  // ---- persistent bf16 weights ----
  u16* w_in1T = (u16*)alloc((size_t)256*128*2);
  u16* w_in2T = (u16*)alloc((size_t)512*256*2);
  u16* qkT  = (u16*)alloc((size_t)LL*1024*512*2);    // [l][q-cols|k-cols][512]
  u16* wvT  = (u16*)alloc((size_t)LL*512*512*2);
  u16* woT  = (u16*)alloc((size_t)LL*512*512*2);
  u16* gwT  = (u16*)alloc((size_t)LL*512*512*2);
  u16* fw1T = (u16*)alloc((size_t)3072*512*2);       // per-layer slots
  u16* fw2T = (u16*)alloc((size_t)3072*3072*2);
  u16* fw3T = (u16*)alloc((size_t)512*3072*2);
  u16* pkwT = (u16*)alloc((size_t)512*512*2);
  u16* pvwT = (u16*)alloc((size_t)512*512*2);
  u16* powT = (u16*)alloc((size_t)512*512*2);
  u16* pqwT = (u16*)alloc((size_t)512*512*2);
  u16* hw1T = (u16*)alloc((size_t)TT*1024*1024*2);
  u16* hw2T = (u16*)alloc((size_t)TT*512*1024*2);
  u16* hw3T = (u16*)alloc((size_t)TT*256*512*2);
  u16* uw1T = (u16*)alloc((size_t)TT*256*1024*2);
  float* bqk = (float*)alloc((size_t)LL*1024*4);

  // ---- shared activations ----
  u16* hB16 = (u16*)alloc((size_t)N1P*DD*2);         // post-n1; ctx; xs
  u16* qk16 = (u16*)alloc((size_t)N1P*1024*2);       // q|k; later gate + tmp
  u16* gate16 = qk16;
  u16* tmp16  = qk16 + (size_t)N1P*512;
  // small tails
  u16* pq16   = (u16*)alloc(512*2);
  float* qvec = (float*)alloc(512*4);
  u16* po16   = (u16*)alloc((size_t)128*512*2);
  u16* po2bf  = (u16*)alloc((size_t)128*512*2);
  u16* c384   = (u16*)alloc((size_t)384*1024*2);
  u16* hh0 = (u16*)alloc((size_t)384*1024*2);
  u16* hh1 = (u16*)alloc((size_t)384*1024*2);
  u16* hh2 = (u16*)alloc((size_t)384*512*2);
  u16* hh3 = (u16*)alloc((size_t)384*256*2);
  u16* uu  = (u16*)alloc((size_t)384*256*2);

  // ---- branch region: big (full fbuf2 overlapping v/hA) vs small (chunked f_w3) ----
  const size_t off_common = off;
  // big layout
  size_t off_big;
  u16 *fbuf1_b, *v16_b, *hA16_b, *fbuf2_b, *vT_b;
  {
    off = off_common;
    fbuf1_b = (u16*)alloc(FB1*2);
    v16_b   = (u16*)alloc((size_t)N1P*512*2);
    hA16_b  = (u16*)alloc((size_t)N1P*512*2);
    alloc((size_t)N1P*2048*2);                       // fbuf2 extra
    fbuf2_b = v16_b;
    vT_b    = fbuf2_b + (size_t)N1P*1024;
    off_big = off;
  }
  // small layout
  u16 *fbuf1_s, *fbuf2_s, *v16_s, *hA16_s, *vT_s;
  {
    off = off_common;
    fbuf1_s = (u16*)alloc(FB1*2);
    fbuf2_s = (u16*)alloc(FB1*2);
    v16_s   = (u16*)alloc((size_t)N1P*512*2);
    hA16_s  = (u16*)alloc((size_t)N1P*512*2);
    vT_s    = fbuf1_s;                               // spans fbuf1+fbuf2 (contiguous)
  }
  const bool big = ws_size >= off_big;
  u16* fbuf1 = big ? fbuf1_b : fbuf1_s;
  u16* fbuf2 = big ? fbuf2_b : fbuf2_s;
  u16* v16   = big ? v16_b   : v16_s;
  u16* hA16  = big ? hA16_b  : hA16_s;
  u16* vT    = big ? vT_b    : vT_s;
  u16* x16 = fbuf1;
  u16* t1b = fbuf1 + 3670016;

  const dim3 tb(32,8);
  transcvt<<<dim3(4,8,1),   tb, 0, stream>>>(in_w1, w_in1T, 128, 256, 0);
  transcvt<<<dim3(8,16,1),  tb, 0, stream>>>(in_w2, w_in2T, 256, 512, 0);
  transcvt<<<dim3(16,16,LL),tb, 0, stream>>>(wq,  qkT,             512, 512, (size_t)1024*512);
  transcvt<<<dim3(16,16,LL),tb, 0, stream>>>(wk,  qkT + 512*512,   512, 512, (size_t)1024*512);
  transcvt<<<dim3(16,16,LL),tb, 0, stream>>>(wv,  wvT, 512, 512, (size_t)512*512);
  transcvt<<<dim3(16,16,LL),tb, 0, stream>>>(wo,  woT, 512, 512, (size_t)512*512);
  transcvt<<<dim3(16,16,LL),tb, 0, stream>>>(g_w, gwT, 512, 512, (size_t)512*512);
  transcvt<<<dim3(16,16,1), tb, 0, stream>>>(pkw,   pkwT, 512, 512, 0);
  transcvt<<<dim3(16,16,1), tb, 0, stream>>>(pvw,   pvwT, 512, 512, 0);
  transcvt<<<dim3(16,16,1), tb, 0, stream>>>(pow_w, powT, 512, 512, 0);
  transcvt<<<dim3(16,16,1), tb, 0, stream>>>(pqw,   pqwT, 512, 512, 0);
  transcvt<<<dim3(32,32,TT),tb, 0, stream>>>(h_w1, hw1T, 1024, 1024, (size_t)1024*1024);
  transcvt<<<dim3(32,16,TT),tb, 0, stream>>>(h_w2, hw2T, 1024, 512, (size_t)512*1024);
  transcvt<<<dim3(16,8,TT), tb, 0, stream>>>(h_w3, hw3T, 512, 256, (size_t)256*512);
  transcvt<<<dim3(32,8,TT), tb, 0, stream>>>(u_w1, uw1T, 1024, 256, (size_t)256*1024);
  biascat<<<24,256,0,stream>>>(bq, bk, bqk);

  cvt<<<(NS*128+255)/256, 256, 0, stream>>>(x,  x16,  NS*128);
  cvt<<<2, 256, 0, stream>>>(pqv, pq16, 512);

  // input MLP
  gemm128<1,0,0><<<dim3(224,2),256,0,stream>>>(x16,128, w_in1T,128, in_b1, t1b,256, nullptr, 128);
  gemm128<0,0,0><<<dim3(224,4),256,0,stream>>>(t1b,256, w_in2T,256, in_b2, tmp16,512, nullptr, 256);
  ln_pos_cls<<<N1,256,0,stream>>>(tmp16, in_lnw, in_lnb, pos, cls, hA16);

  static const int CH_T[8] = {29,28,28,28,28,28,28,28};

  for (int i=0;i<LL;i++){
    const size_t wOff = (size_t)i*512*512;
    transcvt<<<dim3(16,96,1),tb,0,stream>>>(f_w1 + (size_t)i*512*3072,  fw1T, 512, 3072, 0);
    transcvt<<<dim3(96,96,1),tb,0,stream>>>(f_w2 + (size_t)i*3072*3072, fw2T, 3072, 3072, 0);
    transcvt<<<dim3(96,16,1),tb,0,stream>>>(f_w3 + (size_t)i*3072*512,  fw3T, 3072, 512, 0);

    gemm128<0,0,0><<<dim3(225,8),256,0,stream>>>(hA16,512, qkT+(size_t)i*1024*512,512, bqk+i*1024, qk16,1024, nullptr, 512);
    gemm128<0,0,0><<<dim3(225,4),256,0,stream>>>(hA16,512, wvT+wOff,512, bv+i*512, v16,512, nullptr, 512);
    vtrans<<<dim3(15,512),256,0,stream>>>(v16, vT);
    flash_attn<<<4096,256,0,stream>>>(qk16, vT, hB16);
    gemm128<0,0,0><<<dim3(225,4),256,0,stream>>>(hB16,512, woT+wOff,512, bo+i*512, tmp16,512, nullptr, 512);
    attn_merge<<<N1,256,0,stream>>>(hA16, tmp16, conv_w+(size_t)i*1536, conv_b+i*512,
                                    aln_w+i*512, aln_b+i*512, n1_w+i*512, n1_b+i*512, hB16);
    gemm128<2,0,0><<<dim3(225,4),256,0,stream>>>(hB16,512, gwT+wOff,512, g_b+i*512, gate16,512, nullptr, 512);
    if (big) {
      int t0 = 0;
      for (int c=0;c<8;c++){
        const int nt = CH_T[c];
        const size_t r0 = (size_t)t0*128;
        gemm128<1,0,0><<<dim3(nt,24),256,0,stream>>>(hB16 + r0*512, 512, fw1T, 512, f_b1+i*3072, fbuf1, 3072, nullptr, 512);
        gemm128<1,0,0><<<dim3(nt,24),256,0,stream>>>(fbuf1, 3072, fw2T, 3072, f_b2+i*3072, fbuf2 + r0*3072, 3072, nullptr, 3072);
        t0 += nt;
      }
      gemm128<0,1,0><<<dim3(225,4),256,0,stream>>>(fbuf2, 3072, fw3T, 3072, f_b3+i*512, tmp16, 512, gate16, 3072);
    } else {
      int t0 = 0;
      for (int c=0;c<8;c++){
        const int nt = CH_T[c];
        const size_t r0 = (size_t)t0*128;
        gemm128<1,0,0><<<dim3(nt,24),256,0,stream>>>(hB16 + r0*512, 512, fw1T, 512, f_b1+i*3072, fbuf1, 3072, nullptr, 512);
        gemm128<1,0,0><<<dim3(nt,24),256,0,stream>>>(fbuf1, 3072, fw2T, 3072, f_b2+i*3072, fbuf2, 3072, nullptr, 3072);
        gemm128<0,1,0><<<dim3(nt,4), 256,0,stream>>>(fbuf2, 3072, fw3T, 3072, f_b3+i*512, tmp16 + r0*512, 512, gate16 + r0*512, 3072);
        t0 += nt;
      }
    }
    resid_ln<<<N1,256,0,stream>>>(hB16, tmp16, n2_w+i*512, n2_b+i*512, hA16);
  }

  // pooling attention
  xs_compact<<<NS*64/256,256,0,stream>>>(hA16, hB16);
  gemm128<0,0,0><<<dim3(224,4),256,0,stream>>>(hB16,512, pkwT,512, pkb, gate16,512, nullptr, 512);
  gemm128<0,0,0><<<dim3(224,4),256,0,stream>>>(hB16,512, pvwT,512, pvb, tmp16,512, nullptr, 512);
  wavedot<0><<<8,256,0,stream>>>(pq16, 512, pqwT, pqb, qvec, 512);
  pool_attn<<<256,256,0,stream>>>(qvec, gate16, tmp16, po16);
  gemm128<0,0,0><<<dim3(1,4),256,0,stream>>>(po16,512, powT,512, pow_b, po2bf,512, nullptr, 512);
  comb_build<<<64,256,0,stream>>>(hA16, po2bf, pln_w, pln_b, c384);

  // heads (384-row padded, TSEL selects per-head weight block)
  head_ln<<<192,256,0,stream>>>(c384, h_lnw, h_lnb, hh0);
  gemm128<1,0,1><<<dim3(3,8),256,0,stream>>>(hh0,1024, hw1T,1024, h_b1, hh1,1024, nullptr, 1024);
  gemm128<1,0,1><<<dim3(3,4),256,0,stream>>>(hh1,1024, hw2T,1024, h_b2, hh2,512, nullptr, 1024);
  gemm128<1,0,1><<<dim3(3,2),256,0,stream>>>(hh2,512,  hw3T,512,  h_b3, hh3,256, nullptr, 512);
  logits_k<<<3,256,0,stream>>>(hh3, h_w4, h_b4, out);
  gemm128<3,0,1><<<dim3(3,2),256,0,stream>>>(c384,1024, uw1T,1024, u_b1, uu,256, nullptr, 1024);
  u2_k<<<1,256,0,stream>>>(nullptr, uu, u_w2, u_b2, out);
}